// Round 1
// baseline (569.000 us; speedup 1.0000x reference)
//
#include <hip/hip_runtime.h>
#include <cstdint>
#include <cstddef>

// x (B=8, C=64, S=32768) fp32; codebook (512, 64) fp32.
#define SPATIAL   32768
#define CHANNELS  64
#define NUM_EMB   512
#define NPOS      262144
#define OUT_ELEMS 16777216
#define BLOCK     256            // 4 waves; block covers 128 positions (32/wave)
#define POSB      128
#define LOSS_SCALE (1.25f / 16777216.0f)

typedef __attribute__((ext_vector_type(8))) short bf16x8;
typedef __attribute__((ext_vector_type(4))) float f32x4;

union b8u { int i[4]; bf16x8 v; };
union fiu { float f; unsigned u; };

// fp32 -> bf16 RNE (prep only)
__device__ __forceinline__ short f2bf_rne(float f) {
    fiu v; v.f = f;
    unsigned r = v.u + 0x7fffu + ((v.u >> 16) & 1u);
    return (short)(r >> 16);
}

// Prep: cbbf = bf16(codebook), cbn[e] = -0.5*||cb_e||^2, zero loss slot.
__global__ void vq_prep(const float* __restrict__ cb,
                        short* __restrict__ cbbf,
                        float* __restrict__ cbn,
                        float* __restrict__ loss_slot) {
    int e = blockIdx.x * blockDim.x + threadIdx.x;
    if (e == 0) *loss_slot = 0.0f;
    if (e < NUM_EMB) {
        float s = 0.0f;
#pragma unroll
        for (int c = 0; c < CHANNELS; ++c) {
            float v = cb[e * CHANNELS + c];
            cbbf[e * CHANNELS + c] = f2bf_rne(v);
            s = __builtin_fmaf(v, v, s);
        }
        cbn[e] = -0.5f * s;
    }
}

// R7: occupancy doubling. Grid was 4096 waves vs 8192 capacity (latency-bound,
// MfmaUtil 9.5 / VALUBusy 40 / Occ 36, HBM 24%). Each wave now owns 32
// positions (2 M-tiles) instead of 64 -> 8192 waves, same total instruction
// work, half the per-wave dependent-chain length. Epilogue: 2 threads/pos
// x 32 channels (needs one barrier; cand[] is cross-wave now).
__global__ __launch_bounds__(BLOCK, 8) void vq_main(
    const float* __restrict__ x,
    const float* __restrict__ cb,
    const short* __restrict__ cbbf,
    const float* __restrict__ cbn,
    float* __restrict__ out,
    float* __restrict__ loss_slot) {
#pragma clang fp contract(off)
    __shared__ int   cand[POSB];
    __shared__ float wsum[4];

    const int tid  = threadIdx.x;
    const int wave = tid >> 6, lane = tid & 63;
    const int q    = lane >> 4, col = lane & 15;

    const int blockPos = blockIdx.x * POSB;       // 128 | 32768 -> whole block same b
    const int b     = blockPos >> 15;
    const int sbase = blockPos & 32767;
    const float* xb = x + (size_t)b * (CHANNELS * SPATIAL);
    const int wbase = sbase + wave * 32;

    // ---- A fragments: wave covers 32 positions = 2 M-tiles of 16 ----
    // A[m=col][k=q*8+j]; bf16 by truncation: one v_perm packs 2 values.
    b8u A[2][2];
#pragma unroll
    for (int t = 0; t < 2; ++t) {
        const unsigned* pu = (const unsigned*)xb + (wbase + t * 16 + col);
#pragma unroll
        for (int kh = 0; kh < 2; ++kh) {
#pragma unroll
            for (int jj = 0; jj < 4; ++jj) {
                unsigned u0 = pu[(size_t)(kh * 32 + q * 8 + 2 * jj + 0) * SPATIAL];
                unsigned u1 = pu[(size_t)(kh * 32 + q * 8 + 2 * jj + 1) * SPATIAL];
                // result = (hi16(u1)<<16) | hi16(u0)
                A[t][kh].i[jj] = __builtin_amdgcn_perm(u1, u0, 0x07060302u);
            }
        }
    }

    // packed running max per (t, r): high 23 bits = score, low 9 bits = 511-e
    float m[2][4];
#pragma unroll
    for (int t = 0; t < 2; ++t)
#pragma unroll
        for (int r = 0; r < 4; ++r) m[t][r] = -3.4e38f;

    const unsigned MASK = 0xFFFFFE00u;
    const int encBase = 511 - col;

    for (int nt = 0; nt < 32; ++nt) {
        const int e0 = nt * 16;
        // B[n=col][k=q*8+j]: entry row e0+col, contiguous bf16 from global (L2-hot)
        const short* brow = cbbf + (size_t)(e0 + col) * CHANNELS + q * 8;
        bf16x8 B0 = *(const bf16x8*)(brow);
        bf16x8 B1 = *(const bf16x8*)(brow + 32);
        float cn = cbn[e0 + col];
        f32x4 ci = {cn, cn, cn, cn};
        const unsigned enc = (unsigned)(encBase - e0);
#pragma unroll
        for (int t = 0; t < 2; ++t) {
            f32x4 acc = __builtin_amdgcn_mfma_f32_16x16x32_bf16(A[t][0].v, B0, ci, 0, 0, 0);
            acc = __builtin_amdgcn_mfma_f32_16x16x32_bf16(A[t][1].v, B1, acc, 0, 0, 0);
#pragma unroll
            for (int r = 0; r < 4; ++r) {
                fiu p; p.f = acc[r];
                p.u = (p.u & MASK) | enc;        // v_and_or_b32
                m[t][r] = fmaxf(m[t][r], p.f);   // v_max_f32
            }
        }
    }

    // ---- cross-lane argmax per position (butterfly over the 16 cols) ----
#pragma unroll
    for (int t = 0; t < 2; ++t) {
#pragma unroll
        for (int r = 0; r < 4; ++r) {
            float v = m[t][r];
#pragma unroll
            for (int d = 1; d < 16; d <<= 1)
                v = fmaxf(v, __shfl_xor(v, d, 64));
            if (col == 0) {
                fiu p; p.f = v;
                cand[wave * 32 + t * 16 + q * 4 + r] = 511 - (int)(p.u & 511u);
            }
        }
    }
    __syncthreads();   // cand[] is read by other waves in the epilogue now

    // ---- epilogue: out = fl(x + fl(q - x)), loss partial ----
    // 2 threads per position: thread (pos, half) does channels half*32..+31.
    const int pos  = tid & (POSB - 1);
    const int half = tid >> 7;
    const int bidx = cand[pos];
    const float* qrow = cb + (size_t)bidx * CHANNELS + half * 32; // contiguous -> b128s
    const float* px = xb + (sbase + pos) + (size_t)(half * 32) * SPATIAL;
    float* op = out + (size_t)b * (CHANNELS * SPATIAL) + (sbase + pos)
                    + (size_t)(half * 32) * SPATIAL;
    float lsum = 0.0f;
#pragma unroll
    for (int c = 0; c < 32; ++c) {
        float xv = px[(size_t)c * SPATIAL];
        float t2 = qrow[c] - xv;
        op[(size_t)c * SPATIAL] = xv + t2;
        lsum = __builtin_fmaf(t2, t2, lsum);
    }

    // block loss reduction -> one atomic
#pragma unroll
    for (int off = 32; off > 0; off >>= 1) lsum += __shfl_down(lsum, off, 64);
    if (lane == 0) wsum[wave] = lsum;
    __syncthreads();
    if (tid == 0) {
        float bs = (wsum[0] + wsum[1]) + (wsum[2] + wsum[3]);
        atomicAdd(loss_slot, bs * LOSS_SCALE);
    }
}

extern "C" void kernel_launch(void* const* d_in, const int* in_sizes, int n_in,
                              void* d_out, int out_size, void* d_ws, size_t ws_size,
                              hipStream_t stream) {
    const float* x  = (const float*)d_in[0];
    const float* cb = (const float*)d_in[1];
    float* out = (float*)d_out;
    short* cbbf = (short*)d_ws;                        // 512*64 bf16 = 64 KB
    float* cbn  = (float*)(cbbf + NUM_EMB * CHANNELS); // 512 floats
    float* loss_slot = out + OUT_ELEMS;

    vq_prep<<<2, 256, 0, stream>>>(cb, cbbf, cbn, loss_slot);
    vq_main<<<NPOS / POSB, BLOCK, 0, stream>>>(x, cb, cbbf, cbn, out, loss_slot);
}

// Round 2
// 234.279 us; speedup vs baseline: 2.4287x; 2.4287x over previous
//
#include <hip/hip_runtime.h>
#include <cstdint>
#include <cstddef>

// x (B=8, C=64, S=32768) fp32; codebook (512, 64) fp32.
#define SPATIAL   32768
#define CHANNELS  64
#define NUM_EMB   512
#define NPOS      262144
#define OUT_ELEMS 16777216
#define BLOCK     256            // 4 waves; block covers 128 positions (32/wave)
#define POSB      128
#define LOSS_SCALE (1.25f / 16777216.0f)

typedef __attribute__((ext_vector_type(8))) short bf16x8;
typedef __attribute__((ext_vector_type(4))) float f32x4;

union b8u { int i[4]; bf16x8 v; };
union fiu { float f; unsigned u; };

// fp32 -> bf16 RNE (prep only)
__device__ __forceinline__ short f2bf_rne(float f) {
    fiu v; v.f = f;
    unsigned r = v.u + 0x7fffu + ((v.u >> 16) & 1u);
    return (short)(r >> 16);
}

// Prep: cbbf = bf16(codebook), cbn[e] = -0.5*||cb_e||^2, zero loss slot.
__global__ void vq_prep(const float* __restrict__ cb,
                        short* __restrict__ cbbf,
                        float* __restrict__ cbn,
                        float* __restrict__ loss_slot) {
    int e = blockIdx.x * blockDim.x + threadIdx.x;
    if (e == 0) *loss_slot = 0.0f;
    if (e < NUM_EMB) {
        float s = 0.0f;
#pragma unroll
        for (int c = 0; c < CHANNELS; ++c) {
            float v = cb[e * CHANNELS + c];
            cbbf[e * CHANNELS + c] = f2bf_rne(v);
            s = __builtin_fmaf(v, v, s);
        }
        cbn[e] = -0.5f * s;
    }
}

// R8: R7's 32-pos/wave decomposition (8192 waves -> full occupancy potential)
// WITHOUT the __launch_bounds__ min-waves hint. R7's (256,8) hint drove the
// allocator to 32 VGPRs -> massive scratch spills (FETCH 67->921 MB, WRITE
// 65->647 MB, VALUBusy 40->3.3%). R6's natural allocation was 56 <= 64, so
// 8 waves/SIMD never needed the hint; this kernel has less live state than
// R6 and should land ~44-52 VGPRs unconstrained.
__global__ __launch_bounds__(BLOCK) void vq_main(
    const float* __restrict__ x,
    const float* __restrict__ cb,
    const short* __restrict__ cbbf,
    const float* __restrict__ cbn,
    float* __restrict__ out,
    float* __restrict__ loss_slot) {
#pragma clang fp contract(off)
    __shared__ int   cand[POSB];
    __shared__ float wsum[4];

    const int tid  = threadIdx.x;
    const int wave = tid >> 6, lane = tid & 63;
    const int q    = lane >> 4, col = lane & 15;

    const int blockPos = blockIdx.x * POSB;       // 128 | 32768 -> whole block same b
    const int b     = blockPos >> 15;
    const int sbase = blockPos & 32767;
    const float* xb = x + (size_t)b * (CHANNELS * SPATIAL);
    const int wbase = sbase + wave * 32;

    // ---- A fragments: wave covers 32 positions = 2 M-tiles of 16 ----
    // A[m=col][k=q*8+j]; bf16 by truncation: one v_perm packs 2 values.
    b8u A[2][2];
#pragma unroll
    for (int t = 0; t < 2; ++t) {
        const unsigned* pu = (const unsigned*)xb + (wbase + t * 16 + col);
#pragma unroll
        for (int kh = 0; kh < 2; ++kh) {
#pragma unroll
            for (int jj = 0; jj < 4; ++jj) {
                unsigned u0 = pu[(size_t)(kh * 32 + q * 8 + 2 * jj + 0) * SPATIAL];
                unsigned u1 = pu[(size_t)(kh * 32 + q * 8 + 2 * jj + 1) * SPATIAL];
                // result = (hi16(u1)<<16) | hi16(u0)
                A[t][kh].i[jj] = __builtin_amdgcn_perm(u1, u0, 0x07060302u);
            }
        }
    }

    // packed running max per (t, r): high 23 bits = score, low 9 bits = 511-e
    float m[2][4];
#pragma unroll
    for (int t = 0; t < 2; ++t)
#pragma unroll
        for (int r = 0; r < 4; ++r) m[t][r] = -3.4e38f;

    const unsigned MASK = 0xFFFFFE00u;
    const int encBase = 511 - col;

    for (int nt = 0; nt < 32; ++nt) {
        const int e0 = nt * 16;
        // B[n=col][k=q*8+j]: entry row e0+col, contiguous bf16 from global (L2-hot)
        const short* brow = cbbf + (size_t)(e0 + col) * CHANNELS + q * 8;
        bf16x8 B0 = *(const bf16x8*)(brow);
        bf16x8 B1 = *(const bf16x8*)(brow + 32);
        float cn = cbn[e0 + col];
        f32x4 ci = {cn, cn, cn, cn};
        const unsigned enc = (unsigned)(encBase - e0);
#pragma unroll
        for (int t = 0; t < 2; ++t) {
            f32x4 acc = __builtin_amdgcn_mfma_f32_16x16x32_bf16(A[t][0].v, B0, ci, 0, 0, 0);
            acc = __builtin_amdgcn_mfma_f32_16x16x32_bf16(A[t][1].v, B1, acc, 0, 0, 0);
#pragma unroll
            for (int r = 0; r < 4; ++r) {
                fiu p; p.f = acc[r];
                p.u = (p.u & MASK) | enc;        // v_and_or_b32
                m[t][r] = fmaxf(m[t][r], p.f);   // v_max_f32
            }
        }
    }

    // ---- cross-lane argmax per position (butterfly over the 16 cols) ----
#pragma unroll
    for (int t = 0; t < 2; ++t) {
#pragma unroll
        for (int r = 0; r < 4; ++r) {
            float v = m[t][r];
#pragma unroll
            for (int d = 1; d < 16; d <<= 1)
                v = fmaxf(v, __shfl_xor(v, d, 64));
            if (col == 0) {
                fiu p; p.f = v;
                cand[wave * 32 + t * 16 + q * 4 + r] = 511 - (int)(p.u & 511u);
            }
        }
    }
    __syncthreads();   // cand[] is read by other waves in the epilogue

    // ---- epilogue: out = fl(x + fl(q - x)), loss partial ----
    // 2 threads per position: thread (pos, half) does channels half*32..+31.
    const int pos  = tid & (POSB - 1);
    const int half = tid >> 7;
    const int bidx = cand[pos];
    const float* qrow = cb + (size_t)bidx * CHANNELS + half * 32; // contiguous -> b128s
    const float* px = xb + (sbase + pos) + (size_t)(half * 32) * SPATIAL;
    float* op = out + (size_t)b * (CHANNELS * SPATIAL) + (sbase + pos)
                    + (size_t)(half * 32) * SPATIAL;
    float lsum = 0.0f;
#pragma unroll
    for (int c = 0; c < 32; ++c) {
        float xv = px[(size_t)c * SPATIAL];
        float t2 = qrow[c] - xv;
        op[(size_t)c * SPATIAL] = xv + t2;
        lsum = __builtin_fmaf(t2, t2, lsum);
    }

    // block loss reduction -> one atomic
#pragma unroll
    for (int off = 32; off > 0; off >>= 1) lsum += __shfl_down(lsum, off, 64);
    if (lane == 0) wsum[wave] = lsum;
    __syncthreads();
    if (tid == 0) {
        float bs = (wsum[0] + wsum[1]) + (wsum[2] + wsum[3]);
        atomicAdd(loss_slot, bs * LOSS_SCALE);
    }
}

extern "C" void kernel_launch(void* const* d_in, const int* in_sizes, int n_in,
                              void* d_out, int out_size, void* d_ws, size_t ws_size,
                              hipStream_t stream) {
    const float* x  = (const float*)d_in[0];
    const float* cb = (const float*)d_in[1];
    float* out = (float*)d_out;
    short* cbbf = (short*)d_ws;                        // 512*64 bf16 = 64 KB
    float* cbn  = (float*)(cbbf + NUM_EMB * CHANNELS); // 512 floats
    float* loss_slot = out + OUT_ELEMS;

    vq_prep<<<2, 256, 0, stream>>>(cb, cbbf, cbn, loss_slot);
    vq_main<<<NPOS / POSB, BLOCK, 0, stream>>>(x, cb, cbbf, cbn, out, loss_slot);
}

// Round 3
// 166.508 us; speedup vs baseline: 3.4172x; 1.4070x over previous
//
#include <hip/hip_runtime.h>
#include <cstdint>
#include <cstddef>

// x (B=8, C=64, S=32768) fp32; codebook (512, 64) fp32.
#define SPATIAL   32768
#define CHANNELS  64
#define NUM_EMB   512
#define NPOS      262144
#define OUT_ELEMS 16777216
#define BLOCK     256            // 4 waves; block covers 128 positions
#define POSB      128
#define LOSS_SCALE (1.25f / 16777216.0f)

typedef __attribute__((ext_vector_type(8))) short bf16x8;
typedef __attribute__((ext_vector_type(4))) float f32x4;

union b8u { int i[4]; bf16x8 v; };
union fiu { float f; unsigned u; };

// fp32 -> bf16 RNE (prep only)
__device__ __forceinline__ short f2bf_rne(float f) {
    fiu v; v.f = f;
    unsigned r = v.u + 0x7fffu + ((v.u >> 16) & 1u);
    return (short)(r >> 16);
}

// Prep: cbbf = bf16(codebook), cbn[e] = -0.5*||cb_e||^2, zero loss slot.
__global__ void vq_prep(const float* __restrict__ cb,
                        short* __restrict__ cbbf,
                        float* __restrict__ cbn,
                        float* __restrict__ loss_slot) {
    int e = blockIdx.x * blockDim.x + threadIdx.x;
    if (e == 0) *loss_slot = 0.0f;
    if (e < NUM_EMB) {
        float s = 0.0f;
#pragma unroll
        for (int c = 0; c < CHANNELS; ++c) {
            float v = cb[e * CHANNELS + c];
            cbbf[e * CHANNELS + c] = f2bf_rne(v);
            s = __builtin_fmaf(v, v, s);
        }
        cbn[e] = -0.5f * s;
    }
}

// R9: entry-split occupancy doubling. R7 (pos-split + (256,8)) spilled to 32
// VGPR; R8 (pos-split, uncapped) inflated to 176 VGPR -- the t=2 body is
// RA-unstable. Keep R6's proven 4-M-tile / 56-VGPR body untouched; each wave
// scores 64 positions x HALF the codebook (16 K-iters). Wave pair combines
// packed (score|511-idx) winners via one fmaxf through LDS -- bit-identical
// to the full-512 max (fmax associative, same tie-break). 8192 waves total.
__global__ __launch_bounds__(BLOCK) void vq_main(
    const float* __restrict__ x,
    const float* __restrict__ cb,
    const short* __restrict__ cbbf,
    const float* __restrict__ cbn,
    float* __restrict__ out,
    float* __restrict__ loss_slot) {
#pragma clang fp contract(off)
    __shared__ float sh_packed[2][POSB];
    __shared__ float wsum[4];

    const int tid  = threadIdx.x;
    const int wave = tid >> 6, lane = tid & 63;
    const int q    = lane >> 4, col = lane & 15;
    const int g    = wave >> 1;          // position group (0,1): 64 positions each
    const int h    = wave & 1;           // codebook half (0,1): 256 entries each

    const int blockPos = blockIdx.x * POSB;       // 128 | 32768 -> whole block same b
    const int b     = blockPos >> 15;
    const int sbase = blockPos & 32767;
    const float* xb = x + (size_t)b * (CHANNELS * SPATIAL);
    const int wbase = sbase + g * 64;

    // ---- A fragments: wave covers 64 positions = 4 M-tiles of 16 ----
    // A[m=col][k=q*8+j]; bf16 by truncation: one v_perm packs 2 values.
    b8u A[4][2];
#pragma unroll
    for (int t = 0; t < 4; ++t) {
        const unsigned* pu = (const unsigned*)xb + (wbase + t * 16 + col);
#pragma unroll
        for (int kh = 0; kh < 2; ++kh) {
#pragma unroll
            for (int jj = 0; jj < 4; ++jj) {
                unsigned u0 = pu[(size_t)(kh * 32 + q * 8 + 2 * jj + 0) * SPATIAL];
                unsigned u1 = pu[(size_t)(kh * 32 + q * 8 + 2 * jj + 1) * SPATIAL];
                // result = (hi16(u1)<<16) | hi16(u0)
                A[t][kh].i[jj] = __builtin_amdgcn_perm(u1, u0, 0x07060302u);
            }
        }
    }

    // packed running max per (t, r): high 23 bits = score, low 9 bits = 511-e
    float m[4][4];
#pragma unroll
    for (int t = 0; t < 4; ++t)
#pragma unroll
        for (int r = 0; r < 4; ++r) m[t][r] = -3.4e38f;

    const unsigned MASK = 0xFFFFFE00u;
    const int encBase = 511 - col;

#pragma unroll 1
    for (int nt = 0; nt < 16; ++nt) {
        const int e0 = h * 256 + nt * 16;
        // B[n=col][k=q*8+j]: entry row e0+col, contiguous bf16 from global (L2-hot)
        const short* brow = cbbf + (size_t)(e0 + col) * CHANNELS + q * 8;
        bf16x8 B0 = *(const bf16x8*)(brow);
        bf16x8 B1 = *(const bf16x8*)(brow + 32);
        float cn = cbn[e0 + col];
        f32x4 ci = {cn, cn, cn, cn};
        const unsigned enc = (unsigned)(encBase - e0);
#pragma unroll
        for (int t = 0; t < 4; ++t) {
            f32x4 acc = __builtin_amdgcn_mfma_f32_16x16x32_bf16(A[t][0].v, B0, ci, 0, 0, 0);
            acc = __builtin_amdgcn_mfma_f32_16x16x32_bf16(A[t][1].v, B1, acc, 0, 0, 0);
#pragma unroll
            for (int r = 0; r < 4; ++r) {
                fiu p; p.f = acc[r];
                p.u = (p.u & MASK) | enc;        // v_and_or_b32
                m[t][r] = fmaxf(m[t][r], p.f);   // v_max_f32
            }
        }
    }

    // ---- cross-lane argmax per position (butterfly over the 16 cols) ----
#pragma unroll
    for (int t = 0; t < 4; ++t) {
#pragma unroll
        for (int r = 0; r < 4; ++r) {
            float v = m[t][r];
#pragma unroll
            for (int d = 1; d < 16; d <<= 1)
                v = fmaxf(v, __shfl_xor(v, d, 64));
            if (col == 0)
                sh_packed[h][g * 64 + t * 16 + q * 4 + r] = v;
        }
    }
    __syncthreads();   // combine halves + cand read cross-wave

    // ---- epilogue: out = fl(x + fl(q - x)), loss partial ----
    // 2 threads per position: thread (pos, half) does channels half*32..+31.
    const int pos  = tid & (POSB - 1);
    const int half = tid >> 7;
    float vmax = fmaxf(sh_packed[0][pos], sh_packed[1][pos]);
    fiu pv; pv.f = vmax;
    const int bidx = 511 - (int)(pv.u & 511u);

    const float* qrow = cb + (size_t)bidx * CHANNELS + half * 32; // contiguous -> b128s
    const float* px = xb + (sbase + pos) + (size_t)(half * 32) * SPATIAL;
    float* op = out + (size_t)b * (CHANNELS * SPATIAL) + (sbase + pos)
                    + (size_t)(half * 32) * SPATIAL;
    float lsum = 0.0f;
#pragma unroll
    for (int c = 0; c < 32; ++c) {
        float xv = px[(size_t)c * SPATIAL];
        float t2 = qrow[c] - xv;
        op[(size_t)c * SPATIAL] = xv + t2;
        lsum = __builtin_fmaf(t2, t2, lsum);
    }

    // block loss reduction -> one atomic
#pragma unroll
    for (int off = 32; off > 0; off >>= 1) lsum += __shfl_down(lsum, off, 64);
    if (lane == 0) wsum[wave] = lsum;
    __syncthreads();
    if (tid == 0) {
        float bs = (wsum[0] + wsum[1]) + (wsum[2] + wsum[3]);
        atomicAdd(loss_slot, bs * LOSS_SCALE);
    }
}

extern "C" void kernel_launch(void* const* d_in, const int* in_sizes, int n_in,
                              void* d_out, int out_size, void* d_ws, size_t ws_size,
                              hipStream_t stream) {
    const float* x  = (const float*)d_in[0];
    const float* cb = (const float*)d_in[1];
    float* out = (float*)d_out;
    short* cbbf = (short*)d_ws;                        // 512*64 bf16 = 64 KB
    float* cbn  = (float*)(cbbf + NUM_EMB * CHANNELS); // 512 floats
    float* loss_slot = out + OUT_ELEMS;

    vq_prep<<<2, 256, 0, stream>>>(cb, cbbf, cbn, loss_slot);
    vq_main<<<NPOS / POSB, BLOCK, 0, stream>>>(x, cb, cbbf, cbn, out, loss_slot);
}

// Round 4
// 149.220 us; speedup vs baseline: 3.8132x; 1.1159x over previous
//
#include <hip/hip_runtime.h>
#include <cstdint>
#include <cstddef>

// x (B=8, C=64, S=32768) fp32; codebook (512, 64) fp32.
#define SPATIAL   32768
#define CHANNELS  64
#define NUM_EMB   512
#define NPOS      262144
#define OUT_ELEMS 16777216
#define BLOCK     256            // 4 waves; block covers 256 positions (64/wave)
#define LOSS_SCALE (1.25f / 16777216.0f)

typedef __attribute__((ext_vector_type(8))) short bf16x8;
typedef __attribute__((ext_vector_type(4))) float f32x4;

union b8u { int i[4]; bf16x8 v; };
union fiu { float f; unsigned u; };

// fp32 -> bf16 RNE (prep only)
__device__ __forceinline__ short f2bf_rne(float f) {
    fiu v; v.f = f;
    unsigned r = v.u + 0x7fffu + ((v.u >> 16) & 1u);
    return (short)(r >> 16);
}

// Prep: write codebook in MFMA B-fragment order + cbn[e] = -0.5*||cb_e||^2.
// Fragment layout: tile nt (16 entries), lane l = q*16+col:
//   cbfrag[nt*1024 + l*8 + j]       = bf16(cb[e0+col][q*8+j])      (B0 chunk)
//   cbfrag[nt*1024 + 512 + l*8 + j] = bf16(cb[e0+col][32+q*8+j])   (B1 chunk)
// Main-kernel B-load becomes lane-contiguous dwordx4 (8 lines/inst vs 16).
__global__ void vq_prep(const float* __restrict__ cb,
                        short* __restrict__ cbfrag,
                        float* __restrict__ cbn,
                        float* __restrict__ loss_slot) {
    int e = blockIdx.x * blockDim.x + threadIdx.x;
    if (e == 0) *loss_slot = 0.0f;
    if (e < NUM_EMB) {
        const int nt  = e >> 4;
        const int col = e & 15;
        float s = 0.0f;
#pragma unroll
        for (int q = 0; q < 4; ++q) {
#pragma unroll
            for (int j = 0; j < 8; ++j) {
                float v0 = cb[e * CHANNELS + q * 8 + j];
                float v1 = cb[e * CHANNELS + 32 + q * 8 + j];
                cbfrag[nt * 1024 + (q * 16 + col) * 8 + j]       = f2bf_rne(v0);
                cbfrag[nt * 1024 + 512 + (q * 16 + col) * 8 + j] = f2bf_rne(v1);
            }
        }
#pragma unroll
        for (int c = 0; c < CHANNELS; ++c) {
            float v = cb[e * CHANNELS + c];
            s = __builtin_fmaf(v, v, s);
        }
        cbn[e] = -0.5f * s;
    }
}

// R10: line-transaction reduction. R6/R9 showed a latency/queue-bound regime
// (HBM 25%, Mfma 8.5%, VALU 40%, 2x waves no help). Dominant hidden resource:
// L1 line-touches per wave-inst. Old B-load touched 16 lines/inst (rows
// 128B-strided across lanes); fragment-layout cbfrag makes it lane-contiguous
// (8 lines/inst, coalesced). Epilogue qrow gather vectorized to float4
// (16B per line-touch instead of 4B). Scores and output math bit-identical
// to R6 (same bf16 rounding, same fma order).
__global__ __launch_bounds__(BLOCK) void vq_main(
    const float* __restrict__ x,
    const float* __restrict__ cb,
    const short* __restrict__ cbfrag,
    const float* __restrict__ cbn,
    float* __restrict__ out,
    float* __restrict__ loss_slot) {
#pragma clang fp contract(off)
    __shared__ int   cand[BLOCK];
    __shared__ float wsum[4];

    const int tid  = threadIdx.x;
    const int wave = tid >> 6, lane = tid & 63;
    const int q    = lane >> 4, col = lane & 15;

    const int blockPos = blockIdx.x * BLOCK;      // 256 | 32768 -> whole block same b
    const int b     = blockPos >> 15;
    const int sbase = blockPos & 32767;
    const float* xb = x + (size_t)b * (CHANNELS * SPATIAL);
    const int wbase = sbase + wave * 64;

    // ---- A fragments: wave covers 64 positions = 4 M-tiles of 16 ----
    // A[m=col][k=q*8+j]; bf16 by truncation: one v_perm packs 2 values.
    b8u A[4][2];
#pragma unroll
    for (int t = 0; t < 4; ++t) {
        const unsigned* pu = (const unsigned*)xb + (wbase + t * 16 + col);
#pragma unroll
        for (int kh = 0; kh < 2; ++kh) {
#pragma unroll
            for (int jj = 0; jj < 4; ++jj) {
                unsigned u0 = pu[(size_t)(kh * 32 + q * 8 + 2 * jj + 0) * SPATIAL];
                unsigned u1 = pu[(size_t)(kh * 32 + q * 8 + 2 * jj + 1) * SPATIAL];
                // result = (hi16(u1)<<16) | hi16(u0)
                A[t][kh].i[jj] = __builtin_amdgcn_perm(u1, u0, 0x07060302u);
            }
        }
    }

    // packed running max per (t, r): high 23 bits = score, low 9 bits = 511-e
    float m[4][4];
#pragma unroll
    for (int t = 0; t < 4; ++t)
#pragma unroll
        for (int r = 0; r < 4; ++r) m[t][r] = -3.4e38f;

    const unsigned MASK = 0xFFFFFE00u;
    const int encBase = 511 - col;

    for (int nt = 0; nt < 32; ++nt) {
        const int e0 = nt * 16;
        // B fragments: lane-contiguous 16B chunks (coalesced, 8 lines/inst)
        const short* fbase = cbfrag + nt * 1024 + lane * 8;
        bf16x8 B0 = *(const bf16x8*)(fbase);
        bf16x8 B1 = *(const bf16x8*)(fbase + 512);
        float cn = cbn[e0 + col];
        f32x4 ci = {cn, cn, cn, cn};
        const unsigned enc = (unsigned)(encBase - e0);
#pragma unroll
        for (int t = 0; t < 4; ++t) {
            f32x4 acc = __builtin_amdgcn_mfma_f32_16x16x32_bf16(A[t][0].v, B0, ci, 0, 0, 0);
            acc = __builtin_amdgcn_mfma_f32_16x16x32_bf16(A[t][1].v, B1, acc, 0, 0, 0);
#pragma unroll
            for (int r = 0; r < 4; ++r) {
                fiu p; p.f = acc[r];
                p.u = (p.u & MASK) | enc;        // v_and_or_b32
                m[t][r] = fmaxf(m[t][r], p.f);   // v_max_f32
            }
        }
    }

    // ---- cross-lane argmax per position (butterfly over the 16 cols) ----
#pragma unroll
    for (int t = 0; t < 4; ++t) {
#pragma unroll
        for (int r = 0; r < 4; ++r) {
            float v = m[t][r];
#pragma unroll
            for (int d = 1; d < 16; d <<= 1)
                v = fmaxf(v, __shfl_xor(v, d, 64));
            if (col == 0) {
                fiu p; p.f = v;
                cand[wave * 64 + t * 16 + q * 4 + r] = 511 - (int)(p.u & 511u);
            }
        }
    }
    // cand written and read by the same wave -> intra-wave LDS order, no barrier

    // ---- epilogue: out = fl(x + fl(q - x)), loss partial ----
    const int bidx = cand[tid];
    const f32x4* qv = (const f32x4*)(cb + (size_t)bidx * CHANNELS); // 256B-aligned rows
    const float* px = xb + (sbase + tid);
    float* op = out + (size_t)b * (CHANNELS * SPATIAL) + (sbase + tid);
    float lsum = 0.0f;
#pragma unroll
    for (int c4 = 0; c4 < 16; ++c4) {
        f32x4 qq = qv[c4];
#pragma unroll
        for (int j = 0; j < 4; ++j) {
            const int c = c4 * 4 + j;
            float xv = px[(size_t)c * SPATIAL];
            float t2 = qq[j] - xv;
            op[(size_t)c * SPATIAL] = xv + t2;
            lsum = __builtin_fmaf(t2, t2, lsum);
        }
    }

    // block loss reduction -> one atomic
#pragma unroll
    for (int off = 32; off > 0; off >>= 1) lsum += __shfl_down(lsum, off, 64);
    if (lane == 0) wsum[wave] = lsum;
    __syncthreads();
    if (tid == 0) {
        float bs = (wsum[0] + wsum[1]) + (wsum[2] + wsum[3]);
        atomicAdd(loss_slot, bs * LOSS_SCALE);
    }
}

extern "C" void kernel_launch(void* const* d_in, const int* in_sizes, int n_in,
                              void* d_out, int out_size, void* d_ws, size_t ws_size,
                              hipStream_t stream) {
    const float* x  = (const float*)d_in[0];
    const float* cb = (const float*)d_in[1];
    float* out = (float*)d_out;
    short* cbfrag = (short*)d_ws;                         // 512*64 bf16 = 64 KB, fragment order
    float* cbn    = (float*)(cbfrag + NUM_EMB * CHANNELS); // 512 floats
    float* loss_slot = out + OUT_ELEMS;

    vq_prep<<<2, 256, 0, stream>>>(cb, cbfrag, cbn, loss_slot);
    vq_main<<<NPOS / BLOCK, BLOCK, 0, stream>>>(x, cb, cbfrag, cbn, out, loss_slot);
}

// Round 5
// 141.614 us; speedup vs baseline: 4.0180x; 1.0537x over previous
//
#include <hip/hip_runtime.h>
#include <cstdint>
#include <cstddef>

// x (B=8, C=64, S=32768) fp32; codebook (512, 64) fp32.
#define SPATIAL   32768
#define CHANNELS  64
#define NUM_EMB   512
#define NPOS      262144
#define OUT_ELEMS 16777216
#define BLOCK     256            // 4 waves; block covers 256 positions (64/wave)
#define LOSS_SCALE (1.25f / 16777216.0f)

#define NT_TOTAL     32
#define NT_PER_CHUNK 8
#define NCHUNK       4
#define CHUNK_BYTES  16384       // 8 tiles * 2KB

typedef __attribute__((ext_vector_type(8))) short bf16x8;
typedef __attribute__((ext_vector_type(4))) float f32x4;

union b8u { int i[4]; bf16x8 v; };
union fiu { float f; unsigned u; };

// fp32 -> bf16 RNE (prep only)
__device__ __forceinline__ short f2bf_rne(float f) {
    fiu v; v.f = f;
    unsigned r = v.u + 0x7fffu + ((v.u >> 16) & 1u);
    return (short)(r >> 16);
}

// Prep: write codebook in MFMA B-fragment order + cbn[e] = -0.5*||cb_e||^2.
// Fragment layout: tile nt (16 entries), lane l = q*16+col:
//   cbfrag[nt*1024 + l*8 + j]       = bf16(cb[e0+col][q*8+j])      (B0 chunk)
//   cbfrag[nt*1024 + 512 + l*8 + j] = bf16(cb[e0+col][32+q*8+j])   (B1 chunk)
// Lane-contiguous 16B chunks -> directly global_load_lds-compatible (linear).
__global__ void vq_prep(const float* __restrict__ cb,
                        short* __restrict__ cbfrag,
                        float* __restrict__ cbn,
                        float* __restrict__ loss_slot) {
    int e = blockIdx.x * blockDim.x + threadIdx.x;
    if (e == 0) *loss_slot = 0.0f;
    if (e < NUM_EMB) {
        const int nt  = e >> 4;
        const int col = e & 15;
        float s = 0.0f;
#pragma unroll
        for (int q = 0; q < 4; ++q) {
#pragma unroll
            for (int j = 0; j < 8; ++j) {
                float v0 = cb[e * CHANNELS + q * 8 + j];
                float v1 = cb[e * CHANNELS + 32 + q * 8 + j];
                cbfrag[nt * 1024 + (q * 16 + col) * 8 + j]       = f2bf_rne(v0);
                cbfrag[nt * 1024 + 512 + (q * 16 + col) * 8 + j] = f2bf_rne(v1);
            }
        }
#pragma unroll
        for (int c = 0; c < CHANNELS; ++c) {
            float v = cb[e * CHANNELS + c];
            s = __builtin_fmaf(v, v, s);
        }
        cbn[e] = -0.5f * s;
    }
}

// R11: line-transaction reduction, part 2 (R10 confirmed the regime: cutting
// txns 2.6K->2.1K/wave bought 13%; nothing else saturated).
//  (a) B-fragments staged once per block into LDS via global_load_lds
//      (double-buffered 4x8-tile chunks) -> score-loop B moves to ds_read_b128
//      (LDS pipe), B txns 544/wave -> 128/wave share.
//  (b) Epilogue codebook gather: 8 lanes/row (128B = 1 line per row-slice,
//      8 txns/inst) through a 32KB XOR-swizzled LDS redistribution buffer,
//      2 channel-chunks of 32. Gather txns 1024 -> 128/wave.
// qbuf aliases the staging arena (time-disjoint). Outputs bit-identical to R10.
__global__ __launch_bounds__(BLOCK) void vq_main(
    const float* __restrict__ x,
    const float* __restrict__ cb,
    const short* __restrict__ cbfrag,
    const float* __restrict__ cbn,
    float* __restrict__ out,
    float* __restrict__ loss_slot) {
#pragma clang fp contract(off)
    __shared__ __align__(16) char smem[32768];   // stage[2][16KB] | qbuf[256][32]f32
    __shared__ int   cand[BLOCK];
    __shared__ float wsum[4];

    short* stageS = (short*)smem;
    float* qbuf   = (float*)smem;

    const int tid  = threadIdx.x;
    const int wave = tid >> 6, lane = tid & 63;
    const int q    = lane >> 4, col = lane & 15;

    const int blockPos = blockIdx.x * BLOCK;      // 256 | 32768 -> whole block same b
    const int b     = blockPos >> 15;
    const int sbase = blockPos & 32767;
    const float* xb = x + (size_t)b * (CHANNELS * SPATIAL);
    const int wbase = sbase + wave * 64;

    // ---- issue staging of chunk 0 early (async, overlaps A-phase) ----
    {
#pragma unroll
        for (int rd = 0; rd < 4; ++rd) {
            const int off = rd * 4096 + wave * 1024;
            const unsigned* g = (const unsigned*)((const char*)cbfrag + off + lane * 16);
            unsigned* l = (unsigned*)(smem + off);
            __builtin_amdgcn_global_load_lds(
                (const __attribute__((address_space(1))) unsigned*)g,
                (__attribute__((address_space(3))) unsigned*)l, 16, 0, 0);
        }
    }

    // ---- A fragments: wave covers 64 positions = 4 M-tiles of 16 ----
    // A[m=col][k=q*8+j]; bf16 by truncation: one v_perm packs 2 values.
    b8u A[4][2];
#pragma unroll
    for (int t = 0; t < 4; ++t) {
        const unsigned* pu = (const unsigned*)xb + (wbase + t * 16 + col);
#pragma unroll
        for (int kh = 0; kh < 2; ++kh) {
#pragma unroll
            for (int jj = 0; jj < 4; ++jj) {
                unsigned u0 = pu[(size_t)(kh * 32 + q * 8 + 2 * jj + 0) * SPATIAL];
                unsigned u1 = pu[(size_t)(kh * 32 + q * 8 + 2 * jj + 1) * SPATIAL];
                // result = (hi16(u1)<<16) | hi16(u0)
                A[t][kh].i[jj] = __builtin_amdgcn_perm(u1, u0, 0x07060302u);
            }
        }
    }

    // packed running max per (t, r): high 23 bits = score, low 9 bits = 511-e
    float m[4][4];
#pragma unroll
    for (int t = 0; t < 4; ++t)
#pragma unroll
        for (int r = 0; r < 4; ++r) m[t][r] = -3.4e38f;

    const unsigned MASK = 0xFFFFFE00u;
    const int encBase = 511 - col;

    __syncthreads();   // chunk 0 staged (barrier drains vmcnt incl. gload_lds)

#pragma unroll 1
    for (int c = 0; c < NCHUNK; ++c) {
        const int buf = c & 1;
        if (c + 1 < NCHUNK) {
            // issue next chunk's staging (drained by end-of-iter barrier)
#pragma unroll
            for (int rd = 0; rd < 4; ++rd) {
                const int off = rd * 4096 + wave * 1024;
                const unsigned* g = (const unsigned*)
                    ((const char*)cbfrag + (c + 1) * CHUNK_BYTES + off + lane * 16);
                unsigned* l = (unsigned*)(smem + (buf ^ 1) * CHUNK_BYTES + off);
                __builtin_amdgcn_global_load_lds(
                    (const __attribute__((address_space(1))) unsigned*)g,
                    (__attribute__((address_space(3))) unsigned*)l, 16, 0, 0);
            }
        }
#pragma unroll
        for (int k = 0; k < NT_PER_CHUNK; ++k) {
            const int nt = c * NT_PER_CHUNK + k;
            const int e0 = nt * 16;
            const short* sb = stageS + buf * (CHUNK_BYTES / 2) + k * 1024 + lane * 8;
            bf16x8 B0 = *(const bf16x8*)sb;
            bf16x8 B1 = *(const bf16x8*)(sb + 512);
            float cn = cbn[e0 + col];
            f32x4 ci = {cn, cn, cn, cn};
            const unsigned enc = (unsigned)(encBase - e0);
#pragma unroll
            for (int t = 0; t < 4; ++t) {
                f32x4 acc = __builtin_amdgcn_mfma_f32_16x16x32_bf16(A[t][0].v, B0, ci, 0, 0, 0);
                acc = __builtin_amdgcn_mfma_f32_16x16x32_bf16(A[t][1].v, B1, acc, 0, 0, 0);
#pragma unroll
                for (int r = 0; r < 4; ++r) {
                    fiu p; p.f = acc[r];
                    p.u = (p.u & MASK) | enc;        // v_and_or_b32
                    m[t][r] = fmaxf(m[t][r], p.f);   // v_max_f32
                }
            }
        }
        __syncthreads();   // publish next chunk; protect buf for overwrite
    }

    // ---- cross-lane argmax per position (butterfly over the 16 cols) ----
#pragma unroll
    for (int t = 0; t < 4; ++t) {
#pragma unroll
        for (int r = 0; r < 4; ++r) {
            float v = m[t][r];
#pragma unroll
            for (int d = 1; d < 16; d <<= 1)
                v = fmaxf(v, __shfl_xor(v, d, 64));
            if (col == 0) {
                fiu p; p.f = v;
                cand[wave * 64 + t * 16 + q * 4 + r] = 511 - (int)(p.u & 511u);
            }
        }
    }
    __syncthreads();   // cand is read cross-wave by the gather; stage arena free

    // ---- epilogue: out = fl(x + fl(q - x)), loss partial ----
    // Two 32-channel chunks. Gather: 8 lanes/row (one 128B line per row-slice),
    // XOR-swizzled LDS redistribution; consume: thread=pos reads its row back.
    const int pos = tid;
    const int gr  = tid >> 3;        // row slot base (0..31)
    const int gl  = tid & 7;         // 16B sub-chunk within 128B row slice
    const float* pxb = xb + (sbase + pos);
    float* opb = out + (size_t)b * (CHANNELS * SPATIAL) + (sbase + pos);
    float lsum = 0.0f;

#pragma unroll 1
    for (int cc = 0; cc < 2; ++cc) {
        // gather 256 rows x 128B slice into qbuf
#pragma unroll
        for (int rd = 0; rd < 8; ++rd) {
            const int r   = rd * 32 + gr;
            const int row = cand[r];
            f32x4 v = *((const f32x4*)(cb + (size_t)row * CHANNELS + cc * 32) + gl);
            const int lsw = gl ^ (r & 7);
            *((f32x4*)(qbuf + r * 32 + lsw * 4)) = v;
        }
        __syncthreads();
        // consume: channels cc*32 .. cc*32+31 for position pos
        const float* px = pxb + (size_t)(cc * 32) * SPATIAL;
        float* op = opb + (size_t)(cc * 32) * SPATIAL;
#pragma unroll
        for (int j = 0; j < 8; ++j) {
            const int jsw = j ^ (pos & 7);
            f32x4 qq = *((const f32x4*)(qbuf + pos * 32 + jsw * 4));
#pragma unroll
            for (int k = 0; k < 4; ++k) {
                const int ch = j * 4 + k;
                float xv = px[(size_t)ch * SPATIAL];
                float t2 = qq[k] - xv;
                op[(size_t)ch * SPATIAL] = xv + t2;
                lsum = __builtin_fmaf(t2, t2, lsum);
            }
        }
        if (cc == 0) __syncthreads();   // qbuf reused by next chunk
    }

    // block loss reduction -> one atomic
#pragma unroll
    for (int off = 32; off > 0; off >>= 1) lsum += __shfl_down(lsum, off, 64);
    if (lane == 0) wsum[wave] = lsum;
    __syncthreads();
    if (tid == 0) {
        float bs = (wsum[0] + wsum[1]) + (wsum[2] + wsum[3]);
        atomicAdd(loss_slot, bs * LOSS_SCALE);
    }
}

extern "C" void kernel_launch(void* const* d_in, const int* in_sizes, int n_in,
                              void* d_out, int out_size, void* d_ws, size_t ws_size,
                              hipStream_t stream) {
    const float* x  = (const float*)d_in[0];
    const float* cb = (const float*)d_in[1];
    float* out = (float*)d_out;
    short* cbfrag = (short*)d_ws;                          // 512*64 bf16 = 64 KB, fragment order
    float* cbn    = (float*)(cbfrag + NUM_EMB * CHANNELS); // 512 floats
    float* loss_slot = out + OUT_ELEMS;

    vq_prep<<<2, 256, 0, stream>>>(cb, cbfrag, cbn, loss_slot);
    vq_main<<<NPOS / BLOCK, BLOCK, 0, stream>>>(x, cb, cbfrag, cbn, out, loss_slot);
}

// Round 6
// 136.363 us; speedup vs baseline: 4.1727x; 1.0385x over previous
//
#include <hip/hip_runtime.h>
#include <cstdint>
#include <cstddef>

// x (B=8, C=64, S=32768) fp32; codebook (512, 64) fp32.
#define SPATIAL   32768
#define CHANNELS  64
#define NUM_EMB   512
#define NPOS      262144
#define OUT_ELEMS 16777216
#define BLOCK     256            // 4 waves; block covers 256 positions (64/wave)
#define LOSS_SCALE (1.25f / 16777216.0f)

typedef __attribute__((ext_vector_type(8))) short bf16x8;
typedef __attribute__((ext_vector_type(4))) float f32x4;

union b8u { int i[4]; bf16x8 v; };
union fiu { float f; unsigned u; };

// fp32 -> bf16 RNE (prep only)
__device__ __forceinline__ short f2bf_rne(float f) {
    fiu v; v.f = f;
    unsigned r = v.u + 0x7fffu + ((v.u >> 16) & 1u);
    return (short)(r >> 16);
}

// Prep: write codebook in MFMA fragment order + cbn[e] = -0.5*||cb_e||^2.
// Fragment layout: tile nt (16 entries), lane l = q*16+col:
//   cbfrag[nt*1024 + l*8 + j]       = bf16(cb[e0+col][q*8+j])      (K-half 0)
//   cbfrag[nt*1024 + 512 + l*8 + j] = bf16(cb[e0+col][32+q*8+j])   (K-half 1)
// Lane-contiguous 16B chunks -> directly global_load_lds-compatible (linear).
__global__ void vq_prep(const float* __restrict__ cb,
                        short* __restrict__ cbfrag,
                        float* __restrict__ cbn,
                        float* __restrict__ loss_slot) {
    int e = blockIdx.x * blockDim.x + threadIdx.x;
    if (e == 0) *loss_slot = 0.0f;
    if (e < NUM_EMB) {
        const int nt  = e >> 4;
        const int col = e & 15;
        float s = 0.0f;
#pragma unroll
        for (int q = 0; q < 4; ++q) {
#pragma unroll
            for (int j = 0; j < 8; ++j) {
                float v0 = cb[e * CHANNELS + q * 8 + j];
                float v1 = cb[e * CHANNELS + 32 + q * 8 + j];
                cbfrag[nt * 1024 + (q * 16 + col) * 8 + j]       = f2bf_rne(v0);
                cbfrag[nt * 1024 + 512 + (q * 16 + col) * 8 + j] = f2bf_rne(v1);
            }
        }
#pragma unroll
        for (int c = 0; c < CHANNELS; ++c) {
            float v = cb[e * CHANNELS + c];
            s = __builtin_fmaf(v, v, s);
        }
        cbn[e] = -0.5f * s;
    }
}

// R12: break the device-wide phase convoy (R11 model: A-read burst ~15us ->
// score ~12us -> epilogue/store ~18us, no overlap; MfmaUtil 11.5% = 7us
// MFMA / 55us dur).
//  (a) x-loads for t2,t3 stay in flight (raw dwords) across score-half-1:
//      perm(t01)'s compiler vmcnt wait also covers the OLDER staging gloads
//      (vmcnt retires in order), so a raw s_barrier (no vmcnt(0) drain)
//      publishes LDS while t23 reads stream under compute.
//  (b) single-shot 32KB staging, one barrier (was 4 chunk barriers w/ drains).
//  (c) swapped-operand MFMA: mfma(cb, x) -> rows=entries, cols=positions;
//      per-position winner becomes lane-local across (r, nt): running max
//      mt[4] (was m[4][4]), butterfly 64 shfl -> 8 shfl. Packed max is
//      order-independent -> bit-identical winner; epilogue unchanged.
__global__ __launch_bounds__(BLOCK) void vq_main(
    const float* __restrict__ x,
    const float* __restrict__ cb,
    const short* __restrict__ cbfrag,
    const float* __restrict__ cbn,
    float* __restrict__ out,
    float* __restrict__ loss_slot) {
#pragma clang fp contract(off)
    __shared__ __align__(16) char smem[32768];   // stage 32KB | later qbuf[256][32]f32
    __shared__ int   cand[BLOCK];
    __shared__ float wsum[4];

    short* stageS = (short*)smem;
    float* qbuf   = (float*)smem;

    const int tid  = threadIdx.x;
    const int wave = tid >> 6, lane = tid & 63;
    const int q    = lane >> 4, col = lane & 15;

    const int blockPos = blockIdx.x * BLOCK;      // 256 | 32768 -> whole block same b
    const int b     = blockPos >> 15;
    const int sbase = blockPos & 32767;
    const float* xb = x + (size_t)b * (CHANNELS * SPATIAL);
    const int wbase = sbase + wave * 64;

    // ---- (1) stage ALL cbfrag (32KB) async; issued FIRST = oldest in vmcnt ----
#pragma unroll
    for (int rd = 0; rd < 8; ++rd) {
        const int off = rd * 4096 + wave * 1024;
        __builtin_amdgcn_global_load_lds(
            (const __attribute__((address_space(1))) unsigned*)
                ((const char*)cbfrag + off + lane * 16),
            (__attribute__((address_space(3))) unsigned*)(smem + off), 16, 0, 0);
    }
    __builtin_amdgcn_sched_barrier(0);   // pin: staging is oldest

    // ---- (2) issue x raw loads: t0,t1 then t2,t3 ----
    unsigned r01[2][2][4][2], r23[2][2][4][2];
#pragma unroll
    for (int t = 0; t < 2; ++t) {
        const unsigned* pu = (const unsigned*)xb + (wbase + t * 16 + col);
#pragma unroll
        for (int kh = 0; kh < 2; ++kh)
#pragma unroll
            for (int jj = 0; jj < 4; ++jj) {
                r01[t][kh][jj][0] = pu[(size_t)(kh * 32 + q * 8 + 2 * jj + 0) * SPATIAL];
                r01[t][kh][jj][1] = pu[(size_t)(kh * 32 + q * 8 + 2 * jj + 1) * SPATIAL];
            }
    }
#pragma unroll
    for (int t = 0; t < 2; ++t) {
        const unsigned* pu = (const unsigned*)xb + (wbase + 32 + t * 16 + col);
#pragma unroll
        for (int kh = 0; kh < 2; ++kh)
#pragma unroll
            for (int jj = 0; jj < 4; ++jj) {
                r23[t][kh][jj][0] = pu[(size_t)(kh * 32 + q * 8 + 2 * jj + 0) * SPATIAL];
                r23[t][kh][jj][1] = pu[(size_t)(kh * 32 + q * 8 + 2 * jj + 1) * SPATIAL];
            }
    }
    __builtin_amdgcn_sched_barrier(0);   // pin: all loads issued above

    // ---- perm t0,t1 fragments (waits its loads; staging is older -> done) ----
    b8u A01[2][2];
#pragma unroll
    for (int t = 0; t < 2; ++t)
#pragma unroll
        for (int kh = 0; kh < 2; ++kh)
#pragma unroll
            for (int jj = 0; jj < 4; ++jj)
                A01[t][kh].i[jj] = __builtin_amdgcn_perm(
                    r01[t][kh][jj][1], r01[t][kh][jj][0], 0x07060302u);

    __builtin_amdgcn_sched_barrier(0);
    __builtin_amdgcn_s_barrier();        // LDS stage visible; t23 loads still in flight
    __builtin_amdgcn_sched_barrier(0);

    // packed running max per position-tile t: high 23 bits score, low 9 = 511-e
    float mt[4];
#pragma unroll
    for (int t = 0; t < 4; ++t) mt[t] = -3.4e38f;
    const unsigned MASK = 0xFFFFFE00u;

    // ---- score half 1: tiles t0,t1 (t23 x-reads stream underneath) ----
#pragma unroll 2
    for (int nt = 0; nt < 32; ++nt) {
        const short* sb = stageS + nt * 1024 + (lane << 3);
        bf16x8 CB0 = *(const bf16x8*)sb;
        bf16x8 CB1 = *(const bf16x8*)(sb + 512);
        f32x4 civ  = *(const f32x4*)(cbn + nt * 16 + (q << 2));
        const unsigned encq = (unsigned)(511 - nt * 16 - (q << 2));
#pragma unroll
        for (int tt = 0; tt < 2; ++tt) {
            f32x4 acc = __builtin_amdgcn_mfma_f32_16x16x32_bf16(CB0, A01[tt][0].v, civ, 0, 0, 0);
            acc = __builtin_amdgcn_mfma_f32_16x16x32_bf16(CB1, A01[tt][1].v, acc, 0, 0, 0);
#pragma unroll
            for (int r = 0; r < 4; ++r) {
                fiu p; p.f = acc[r];
                p.u = (p.u & MASK) | (encq - r);   // entry e0+q*4+r
                mt[tt] = fmaxf(mt[tt], p.f);
            }
        }
    }

    // ---- perm t2,t3 (waits remaining loads), then score half 2 ----
    b8u A23[2][2];
#pragma unroll
    for (int t = 0; t < 2; ++t)
#pragma unroll
        for (int kh = 0; kh < 2; ++kh)
#pragma unroll
            for (int jj = 0; jj < 4; ++jj)
                A23[t][kh].i[jj] = __builtin_amdgcn_perm(
                    r23[t][kh][jj][1], r23[t][kh][jj][0], 0x07060302u);

#pragma unroll 2
    for (int nt = 0; nt < 32; ++nt) {
        const short* sb = stageS + nt * 1024 + (lane << 3);
        bf16x8 CB0 = *(const bf16x8*)sb;
        bf16x8 CB1 = *(const bf16x8*)(sb + 512);
        f32x4 civ  = *(const f32x4*)(cbn + nt * 16 + (q << 2));
        const unsigned encq = (unsigned)(511 - nt * 16 - (q << 2));
#pragma unroll
        for (int tt = 0; tt < 2; ++tt) {
            f32x4 acc = __builtin_amdgcn_mfma_f32_16x16x32_bf16(CB0, A23[tt][0].v, civ, 0, 0, 0);
            acc = __builtin_amdgcn_mfma_f32_16x16x32_bf16(CB1, A23[tt][1].v, acc, 0, 0, 0);
#pragma unroll
            for (int r = 0; r < 4; ++r) {
                fiu p; p.f = acc[r];
                p.u = (p.u & MASK) | (encq - r);
                mt[2 + tt] = fmaxf(mt[2 + tt], p.f);
            }
        }
    }

    // ---- per-position winner: reduce over the 4 q-groups only (2 shfl) ----
#pragma unroll
    for (int t = 0; t < 4; ++t) {
        float v = mt[t];
        v = fmaxf(v, __shfl_xor(v, 16, 64));
        v = fmaxf(v, __shfl_xor(v, 32, 64));
        if (lane < 16) {
            fiu p; p.f = v;
            cand[wave * 64 + t * 16 + lane] = 511 - (int)(p.u & 511u);
        }
    }
    __syncthreads();   // cand cross-wave; stage arena free for qbuf

    // ---- epilogue: out = fl(x + fl(q - x)), loss partial ----
    // Two 32-channel chunks. Gather: 8 lanes/row (one 128B line per row-slice),
    // LDS redistribution; consume: thread=pos reads its row back.
    const int pos = tid;
    const int gr  = tid >> 3;        // row slot base (0..31)
    const int gl  = tid & 7;         // 16B sub-chunk within 128B row slice
    const float* pxb = xb + (sbase + pos);
    float* opb = out + (size_t)b * (CHANNELS * SPATIAL) + (sbase + pos);
    float lsum = 0.0f;

#pragma unroll 1
    for (int cc = 0; cc < 2; ++cc) {
        // gather 256 rows x 128B slice into qbuf
#pragma unroll
        for (int rd = 0; rd < 8; ++rd) {
            const int r   = rd * 32 + gr;
            const int row = cand[r];
            f32x4 v = *((const f32x4*)(cb + (size_t)row * CHANNELS + cc * 32) + gl);
            const int lsw = gl ^ (r & 7);
            *((f32x4*)(qbuf + r * 32 + lsw * 4)) = v;
        }
        __syncthreads();
        // consume: channels cc*32 .. cc*32+31 for position pos
        const float* px = pxb + (size_t)(cc * 32) * SPATIAL;
        float* op = opb + (size_t)(cc * 32) * SPATIAL;
#pragma unroll
        for (int j = 0; j < 8; ++j) {
            const int jsw = j ^ (pos & 7);
            f32x4 qq = *((const f32x4*)(qbuf + pos * 32 + jsw * 4));
#pragma unroll
            for (int k = 0; k < 4; ++k) {
                const int ch = j * 4 + k;
                float xv = px[(size_t)ch * SPATIAL];
                float t2 = qq[k] - xv;
                op[(size_t)ch * SPATIAL] = xv + t2;
                lsum = __builtin_fmaf(t2, t2, lsum);
            }
        }
        if (cc == 0) __syncthreads();   // qbuf reused by next chunk
    }

    // block loss reduction -> one atomic
#pragma unroll
    for (int off = 32; off > 0; off >>= 1) lsum += __shfl_down(lsum, off, 64);
    if (lane == 0) wsum[wave] = lsum;
    __syncthreads();
    if (tid == 0) {
        float bs = (wsum[0] + wsum[1]) + (wsum[2] + wsum[3]);
        atomicAdd(loss_slot, bs * LOSS_SCALE);
    }
}

extern "C" void kernel_launch(void* const* d_in, const int* in_sizes, int n_in,
                              void* d_out, int out_size, void* d_ws, size_t ws_size,
                              hipStream_t stream) {
    const float* x  = (const float*)d_in[0];
    const float* cb = (const float*)d_in[1];
    float* out = (float*)d_out;
    short* cbfrag = (short*)d_ws;                          // 512*64 bf16 = 64 KB, fragment order
    float* cbn    = (float*)(cbfrag + NUM_EMB * CHANNELS); // 512 floats
    float* loss_slot = out + OUT_ELEMS;

    vq_prep<<<2, 256, 0, stream>>>(cb, cbfrag, cbn, loss_slot);
    vq_main<<<NPOS / BLOCK, BLOCK, 0, stream>>>(x, cb, cbfrag, cbn, out, loss_slot);
}